// Round 1
// baseline (114.294 us; speedup 1.0000x reference)
//
#include <hip/hip_runtime.h>

// CuriosityEngine: the goal_sampler path (32x replicated bottleneck + argmax)
// is output-invariant — all 32 action slices are bit-identical, so
// argmax(predicted_entropy) == 0 always. Only the surprise head matters:
//   surprise = relu(mean_T(x).reshape(B,2D) @ W1 + b1) @ W2 + b2   -> (B,)
//   best_action_idx = 0                                            -> scalar
//
// x: (B=4, T=2048, D=768, 2) fp32  => rows of R=1536 floats, reduce over T.

#define BB 4
#define TT 2048
#define RR 1536   // 2*D
#define HH 256

// ---- Kernel 1: column sums of x over T (the 50 MB HBM-bound pass) ----
// grid (64 t-chunks, B), 384 threads = one float4 column each, 32 rows/chunk.
__global__ __launch_bounds__(384) void colsum_kernel(const float* __restrict__ x,
                                                     float* __restrict__ colsum) {
    const int tchunk = blockIdx.x;          // 0..63, 32 rows each
    const int b      = blockIdx.y;
    const int c      = threadIdx.x;         // float4 column 0..383
    const float4* xb = (const float4*)(x + (size_t)b * TT * RR);
    float4 acc = make_float4(0.f, 0.f, 0.f, 0.f);
    const int t0 = tchunk * 32;
    #pragma unroll 8
    for (int tt = 0; tt < 32; ++tt) {
        float4 v = xb[(size_t)(t0 + tt) * (RR / 4) + c];
        acc.x += v.x; acc.y += v.y; acc.z += v.z; acc.w += v.w;
    }
    float* dst = colsum + b * RR + c * 4;
    atomicAdd(dst + 0, acc.x);
    atomicAdd(dst + 1, acc.y);
    atomicAdd(dst + 2, acc.z);
    atomicAdd(dst + 3, acc.w);
}

// ---- Kernel 2: hidden-layer partial sums: hid[b][h] += sum_j sf[b][j]*W1[j][h] ----
// grid (12 j-chunks of 128, B), 256 threads = one h each. W1 reads coalesced
// (thread index == h == fastest-varying W1 dim); sf[j] is a wave broadcast.
__global__ __launch_bounds__(256) void hidden_kernel(const float* __restrict__ colsum,
                                                     const float* __restrict__ W1,
                                                     float* __restrict__ hid) {
    const int b     = blockIdx.y;
    const int jbase = blockIdx.x * 128;
    const int h     = threadIdx.x;
    const float* sfb = colsum + b * RR;
    float acc = 0.f;
    #pragma unroll 8
    for (int jj = 0; jj < 128; ++jj) {
        const int j = jbase + jj;
        acc += sfb[j] * W1[(size_t)j * HH + h];
    }
    // fold the mean's 1/T here (linear), one atomic per (thread, block)
    atomicAdd(&hid[b * HH + h], acc * (1.0f / (float)TT));
}

// ---- Kernel 3: relu(hid + b1) . W2 + b2 per batch; write constant argmax ----
__global__ __launch_bounds__(256) void out_kernel(const float* __restrict__ hid,
                                                  const float* __restrict__ b1,
                                                  const float* __restrict__ W2,
                                                  const float* __restrict__ b2,
                                                  float* __restrict__ out) {
    const int b   = blockIdx.x;
    const int tid = threadIdx.x;
    float v = hid[b * HH + tid] + b1[tid];
    v = fmaxf(v, 0.f);
    v *= W2[tid];
    // wave-64 shuffle reduce, then LDS across the 4 waves
    #pragma unroll
    for (int off = 32; off > 0; off >>= 1) v += __shfl_down(v, off, 64);
    __shared__ float red[4];
    const int lane = tid & 63, wave = tid >> 6;
    if (lane == 0) red[wave] = v;
    __syncthreads();
    if (tid == 0) {
        out[b] = red[0] + red[1] + red[2] + red[3] + b2[0];
        if (b == 0) {
            // best_action_idx: argmax over 32 bit-identical entropies == 0.
            // 0x00000000 is correct under either f32 or i32 readback.
            out[4] = 0.0f;
        }
    }
}

extern "C" void kernel_launch(void* const* d_in, const int* in_sizes, int n_in,
                              void* d_out, int out_size, void* d_ws, size_t ws_size,
                              hipStream_t stream) {
    const float* x  = (const float*)d_in[0];
    const float* W1 = (const float*)d_in[1];
    const float* b1 = (const float*)d_in[2];
    const float* W2 = (const float*)d_in[3];
    const float* b2 = (const float*)d_in[4];
    // d_in[5..8] (Wd, bd, Wu, bu) are unused: the bottleneck path is
    // output-invariant (see header comment).

    float* colsum = (float*)d_ws;           // B*RR fp32 column sums
    float* hid    = colsum + BB * RR;       // B*HH fp32 hidden partials

    // ws is re-poisoned to 0xAA before every launch — zero the accumulators.
    hipMemsetAsync(d_ws, 0, (size_t)(BB * RR + BB * HH) * sizeof(float), stream);

    colsum_kernel<<<dim3(64, BB), 384, 0, stream>>>(x, colsum);
    hidden_kernel<<<dim3(12, BB), 256, 0, stream>>>(colsum, W1, hid);
    out_kernel<<<dim3(BB), 256, 0, stream>>>(hid, b1, W2, b2, (float*)d_out);
}